// Round 1
// baseline (83.970 us; speedup 1.0000x reference)
//
#include <hip/hip_runtime.h>
#include <cstdint>

#define T_STEPS 16
#define V_VECS  1024
#define D_DIM   128
#define B_BATCH 2048
#define NVT     32        // number of v-tiles
#define VT      32        // vectors per tile

// ---------------------------------------------------------------------------
// k_prep: compute invnorm[t*V+v] = rsqrt(max(||L[t,v]||^2, 1e-12)),
//         zero bucket counters and argmax keys (ws re-init every launch).
// 2048 blocks x 256 threads; 8 vectors/block, 32 lanes/vector (coalesced f4).
// ---------------------------------------------------------------------------
__global__ __launch_bounds__(256) void k_prep(const float* __restrict__ L,
                                              int* __restrict__ counts,
                                              unsigned long long* __restrict__ keys,
                                              float* __restrict__ invnrm) {
    const int tid = threadIdx.x, bid = blockIdx.x;
    if (bid == 0 && tid < T_STEPS) counts[tid] = 0;
    if (bid < 8) keys[bid * 256 + tid] = 0ull;

    const int vec = bid * 8 + (tid >> 5);   // 0..16383
    const int lane32 = tid & 31;
    const float4 q = ((const float4*)L)[vec * 32 + lane32];
    float s = q.x * q.x + q.y * q.y + q.z * q.z + q.w * q.w;
    #pragma unroll
    for (int m = 16; m >= 1; m >>= 1) s += __shfl_xor(s, m);
    if (lane32 == 0) invnrm[vec] = rsqrtf(fmaxf(s, 1e-12f));
}

// ---------------------------------------------------------------------------
// k_bucket: scatter b's into per-step lists (order within list irrelevant).
// ---------------------------------------------------------------------------
__global__ __launch_bounds__(256) void k_bucket(const int* __restrict__ idx,
                                                int* __restrict__ counts,
                                                int* __restrict__ lists) {
    const int b = blockIdx.x * 256 + threadIdx.x;   // 8 blocks -> 2048
    const int t = idx[b];
    const int pos = atomicAdd(&counts[t], 1);
    lists[t * B_BATCH + pos] = b;
}

// ---------------------------------------------------------------------------
// k_score: grid (NVT=32, T=16). Stage 32x128 f32 tile into LDS (16B XOR
// swizzle: slot = d4 ^ v, conflict-free for lane-owns-v b128 reads).
// Each wave processes 4 b's per pass: lane (v = lane&31, half = lane>>5)
// accumulates a 64-d half-dot per b, combines via shfl_xor(32), scales by
// invnorm, 5-step butterfly argmax over the 32-v tile (first-index
// tie-break), then atomicMax of packed (ordered_score, 1023-v) key.
// ---------------------------------------------------------------------------
__global__ __launch_bounds__(256) void k_score(const float* __restrict__ X,
                                               const float* __restrict__ L,
                                               const int* __restrict__ counts,
                                               const int* __restrict__ lists,
                                               const float* __restrict__ invnrm,
                                               unsigned long long* __restrict__ keys) {
    __shared__ float4 lds[VT * 32];   // 16 KiB, [v][slot], slot = d4 ^ v

    const int t  = blockIdx.y;
    const int v0 = blockIdx.x * VT;
    const int tid = threadIdx.x;

    // stage latent tile (coalesced f4 global loads, swizzled LDS writes)
    const float4* Lt = (const float4*)(L + (size_t)(t * V_VECS + v0) * D_DIM);
    #pragma unroll
    for (int k = 0; k < 4; ++k) {
        const int id = tid + k * 256;       // 0..1023
        const int v = id >> 5, d4 = id & 31;
        lds[v * 32 + (d4 ^ v)] = Lt[v * 32 + d4];
    }

    const int lane = tid & 63, w = tid >> 6;
    const int vl = lane & 31, h = lane >> 5;
    const float invn = invnrm[t * V_VECS + v0 + vl];
    __syncthreads();

    const int n = counts[t];
    const int* mylist = lists + t * B_BATCH;

    for (int i = w * 4; i < n; i += 16) {
        const int b0 = mylist[i];
        const bool k1 = (i + 1) < n, k2 = (i + 2) < n, k3 = (i + 3) < n;
        const int b1 = k1 ? mylist[i + 1] : b0;
        const int b2 = k2 ? mylist[i + 2] : b0;
        const int b3 = k3 ? mylist[i + 3] : b0;

        const float4* x0 = (const float4*)(X + (size_t)b0 * D_DIM) + h * 16;
        const float4* x1 = (const float4*)(X + (size_t)b1 * D_DIM) + h * 16;
        const float4* x2 = (const float4*)(X + (size_t)b2 * D_DIM) + h * 16;
        const float4* x3 = (const float4*)(X + (size_t)b3 * D_DIM) + h * 16;

        float a0 = 0.f, a1 = 0.f, a2 = 0.f, a3 = 0.f;
        #pragma unroll
        for (int j = 0; j < 16; ++j) {
            const int d4 = h * 16 + j;
            const float4 lv = lds[vl * 32 + (d4 ^ vl)];
            const float4 q0 = x0[j];
            const float4 q1 = x1[j];
            const float4 q2 = x2[j];
            const float4 q3 = x3[j];
            a0 += lv.x * q0.x + lv.y * q0.y + lv.z * q0.z + lv.w * q0.w;
            a1 += lv.x * q1.x + lv.y * q1.y + lv.z * q1.z + lv.w * q1.w;
            a2 += lv.x * q2.x + lv.y * q2.y + lv.z * q2.z + lv.w * q2.w;
            a3 += lv.x * q3.x + lv.y * q3.y + lv.z * q3.z + lv.w * q3.w;
        }
        a0 += __shfl_xor(a0, 32);
        a1 += __shfl_xor(a1, 32);
        a2 += __shfl_xor(a2, 32);
        a3 += __shfl_xor(a3, 32);

        float s0 = a0 * invn, s1 = a1 * invn, s2 = a2 * invn, s3 = a3 * invn;
        int c0 = vl, c1 = vl, c2 = vl, c3 = vl;
        #pragma unroll
        for (int m = 16; m >= 1; m >>= 1) {
            float u; int cu;
            u = __shfl_xor(s0, m); cu = __shfl_xor(c0, m);
            if (u > s0 || (u == s0 && cu < c0)) { s0 = u; c0 = cu; }
            u = __shfl_xor(s1, m); cu = __shfl_xor(c1, m);
            if (u > s1 || (u == s1 && cu < c1)) { s1 = u; c1 = cu; }
            u = __shfl_xor(s2, m); cu = __shfl_xor(c2, m);
            if (u > s2 || (u == s2 && cu < c2)) { s2 = u; c2 = cu; }
            u = __shfl_xor(s3, m); cu = __shfl_xor(c3, m);
            if (u > s3 || (u == s3 && cu < c3)) { s3 = u; c3 = cu; }
        }

        if (lane == 0) {
            auto mk = [&](float s, int c) -> unsigned long long {
                unsigned int ub = __float_as_uint(s);
                ub = (ub & 0x80000000u) ? ~ub : (ub | 0x80000000u);
                return ((unsigned long long)ub << 32) |
                       (unsigned long long)(unsigned)(1023 - (v0 + c));
            };
            atomicMax(&keys[b0], mk(s0, c0));
            if (k1) atomicMax(&keys[b1], mk(s1, c1));
            if (k2) atomicMax(&keys[b2], mk(s2, c2));
            if (k3) atomicMax(&keys[b3], mk(s3, c3));
        }
    }
}

// ---------------------------------------------------------------------------
// k_gather: decode winning v per b, copy raw vector (bit-exact) to out.
// 256 blocks x 256 threads; 8 b's/block, 32 lanes/b (f4 copy).
// ---------------------------------------------------------------------------
__global__ __launch_bounds__(256) void k_gather(const float* __restrict__ L,
                                                const int* __restrict__ idx,
                                                const unsigned long long* __restrict__ keys,
                                                float* __restrict__ out) {
    const int tid = threadIdx.x;
    const int b = blockIdx.x * 8 + (tid >> 5);
    const int lane32 = tid & 31;
    const unsigned long long key = keys[b];
    const int v = 1023 - (int)(key & 0xffffffffull);
    const int t = idx[b];
    ((float4*)out)[b * 32 + lane32] =
        ((const float4*)L)[(size_t)(t * V_VECS + v) * 32 + lane32];
}

extern "C" void kernel_launch(void* const* d_in, const int* in_sizes, int n_in,
                              void* d_out, int out_size, void* d_ws, size_t ws_size,
                              hipStream_t stream) {
    const float* X  = (const float*)d_in[0];   // (B, D, 1) f32
    const float* L  = (const float*)d_in[1];   // (T, V, D) f32
    const int* idx  = (const int*)d_in[2];     // (B,) int
    float* out      = (float*)d_out;           // (B, D) f32

    char* ws = (char*)d_ws;
    int* counts               = (int*)ws;                              // 64 B
    unsigned long long* keys  = (unsigned long long*)(ws + 64);        // 16 KiB
    int* lists                = (int*)(ws + 64 + 16384);               // 128 KiB
    float* invnrm             = (float*)(ws + 64 + 16384 + 131072);    // 64 KiB

    hipLaunchKernelGGL(k_prep,   dim3(2048),          dim3(256), 0, stream, L, counts, keys, invnrm);
    hipLaunchKernelGGL(k_bucket, dim3(8),             dim3(256), 0, stream, idx, counts, lists);
    hipLaunchKernelGGL(k_score,  dim3(NVT, T_STEPS),  dim3(256), 0, stream, X, L, counts, lists, invnrm, keys);
    hipLaunchKernelGGL(k_gather, dim3(256),           dim3(256), 0, stream, L, idx, keys, out);
}

// Round 2
// 42.292 us; speedup vs baseline: 1.9855x; 1.9855x over previous
//
#include <hip/hip_runtime.h>
#include <cstdint>

#define T_STEPS 16
#define V_VECS  1024
#define D_DIM   128
#define B_BATCH 2048

// ---------------------------------------------------------------------------
// k_prep: invnrm[t*V+v] = rsqrt(max(||L[t,v]||^2,1e-12)); zero counts + keys.
// 2048 blocks x 256 threads; 8 vectors/block, 32 lanes/vector.
// ---------------------------------------------------------------------------
__global__ __launch_bounds__(256) void k_prep(const float* __restrict__ L,
                                              int* __restrict__ counts,
                                              unsigned long long* __restrict__ keys,
                                              float* __restrict__ invnrm) {
    const int tid = threadIdx.x, bid = blockIdx.x;
    if (bid == 0 && tid < T_STEPS) counts[tid] = 0;
    if (bid < 8) keys[bid * 256 + tid] = 0ull;

    const int vec = bid * 8 + (tid >> 5);   // 0..16383
    const int lane32 = tid & 31;
    const float4 q = ((const float4*)L)[vec * 32 + lane32];
    float s = q.x * q.x + q.y * q.y + q.z * q.z + q.w * q.w;
    #pragma unroll
    for (int m = 16; m >= 1; m >>= 1) s += __shfl_xor(s, m);
    if (lane32 == 0) invnrm[vec] = rsqrtf(fmaxf(s, 1e-12f));
}

// ---------------------------------------------------------------------------
// k_bucket: scatter b's into per-step lists (order within list irrelevant).
// ---------------------------------------------------------------------------
__global__ __launch_bounds__(256) void k_bucket(const int* __restrict__ idx,
                                                int* __restrict__ counts,
                                                int* __restrict__ lists) {
    const int b = blockIdx.x * 256 + threadIdx.x;   // 8 blocks -> 2048
    const int t = idx[b];
    const int pos = atomicAdd(&counts[t], 1);
    lists[t * B_BATCH + pos] = b;
}

// ---------------------------------------------------------------------------
// k_score: register-tiled fp32 GEMM + fused argmax.
// Grid (16 vtiles, 16 t, 4 bchunks), block 256 = 16(tv) x 16(tb).
// LDS: As[k][v] 32 KB + Xs[k][b] 32 KB (k-major so inner loop does two
// ds_read_b128 per k: A-read 2-way bank aliased (free), X-read broadcast).
// Thread computes 4v x 4b accumulators over k=128 (16 FMA / k).
// Epilogue: scale by invnorm, per-thread argmax over 4 v, 4-step shfl_xor
// butterfly across the 16 tv-lanes, atomicMax packed key per b.
// ---------------------------------------------------------------------------
__global__ __launch_bounds__(256) void k_score(const float* __restrict__ X,
                                               const float* __restrict__ L,
                                               const int* __restrict__ counts,
                                               const int* __restrict__ lists,
                                               const float* __restrict__ invnrm,
                                               unsigned long long* __restrict__ keys) {
    __shared__ __align__(16) float As[D_DIM][64];   // 32 KB
    __shared__ __align__(16) float Xs[D_DIM][64];   // 32 KB

    const int t  = blockIdx.y;
    const int v0 = blockIdx.x * 64;
    const int n  = counts[t];
    const int cs = blockIdx.z * 64;
    if (cs >= n) return;                 // uniform exit, before barrier

    const int tid  = threadIdx.x;
    const int lane = tid & 63;
    const int w    = tid >> 6;

    // ---- stage A^T: row v = lane, float4 col k4 = w + 4p ----
    const float4* LA = (const float4*)(L + (size_t)(t * V_VECS + v0) * D_DIM);
    #pragma unroll
    for (int p = 0; p < 8; ++p) {
        const int k4 = w + 4 * p;              // 0..31
        const float4 g = LA[lane * 32 + k4];
        As[4 * k4 + 0][lane] = g.x;
        As[4 * k4 + 1][lane] = g.y;
        As[4 * k4 + 2][lane] = g.z;
        As[4 * k4 + 3][lane] = g.w;
    }
    // ---- stage X^T: row = bucketed b (zero-pad past n) ----
    const int brow = cs + lane;
    const int bg = (brow < n) ? lists[t * B_BATCH + brow] : -1;
    const float4* XA = (const float4*)X;
    #pragma unroll
    for (int p = 0; p < 8; ++p) {
        const int k4 = w + 4 * p;
        float4 g = make_float4(0.f, 0.f, 0.f, 0.f);
        if (bg >= 0) g = XA[bg * 32 + k4];
        Xs[4 * k4 + 0][lane] = g.x;
        Xs[4 * k4 + 1][lane] = g.y;
        Xs[4 * k4 + 2][lane] = g.z;
        Xs[4 * k4 + 3][lane] = g.w;
    }
    __syncthreads();

    const int tv = tid & 15;     // v-group: v = v0 + tv*4 + i
    const int tb = tid >> 4;     // b-group: b-slot = cs + tb*4 + j

    float acc[4][4] = {};
    #pragma unroll 16
    for (int k = 0; k < D_DIM; ++k) {
        const float4 av = *(const float4*)&As[k][tv * 4];
        const float4 xb = *(const float4*)&Xs[k][tb * 4];
        const float a[4] = {av.x, av.y, av.z, av.w};
        const float x[4] = {xb.x, xb.y, xb.z, xb.w};
        #pragma unroll
        for (int i = 0; i < 4; ++i)
            #pragma unroll
            for (int j = 0; j < 4; ++j)
                acc[i][j] += a[i] * x[j];
    }

    // ---- epilogue: argmax over v per b ----
    const float4 inv4 = *(const float4*)(invnrm + t * V_VECS + v0 + tv * 4);
    const float invp[4] = {inv4.x, inv4.y, inv4.z, inv4.w};

    float bs[4]; int bc[4];
    #pragma unroll
    for (int j = 0; j < 4; ++j) {
        float s = acc[0][j] * invp[0];
        int   c = v0 + tv * 4;
        #pragma unroll
        for (int i = 1; i < 4; ++i) {
            const float si = acc[i][j] * invp[i];
            const int   ci = v0 + tv * 4 + i;
            if (si > s) { s = si; c = ci; }          // strict: lowest v wins tie
        }
        #pragma unroll
        for (int m = 8; m >= 1; m >>= 1) {           // reduce across tv lanes
            const float u  = __shfl_xor(s, m);
            const int   cu = __shfl_xor(c, m);
            if (u > s || (u == s && cu < c)) { s = u; c = cu; }
        }
        bs[j] = s; bc[j] = c;
    }

    if (tv == 0) {
        #pragma unroll
        for (int j = 0; j < 4; ++j) {
            const int bi = cs + tb * 4 + j;
            if (bi < n) {
                const int b = lists[t * B_BATCH + bi];
                unsigned int ub = __float_as_uint(bs[j]);
                ub = (ub & 0x80000000u) ? ~ub : (ub | 0x80000000u);
                const unsigned long long key =
                    ((unsigned long long)ub << 32) |
                    (unsigned long long)(unsigned)(1023 - bc[j]);
                atomicMax(&keys[b], key);
            }
        }
    }
}

// ---------------------------------------------------------------------------
// k_gather: decode winning v per b, copy raw vector (bit-exact) to out.
// ---------------------------------------------------------------------------
__global__ __launch_bounds__(256) void k_gather(const float* __restrict__ L,
                                                const int* __restrict__ idx,
                                                const unsigned long long* __restrict__ keys,
                                                float* __restrict__ out) {
    const int tid = threadIdx.x;
    const int b = blockIdx.x * 8 + (tid >> 5);
    const int lane32 = tid & 31;
    const unsigned long long key = keys[b];
    const int v = 1023 - (int)(key & 0xffffffffull);
    const int t = idx[b];
    ((float4*)out)[b * 32 + lane32] =
        ((const float4*)L)[(size_t)(t * V_VECS + v) * 32 + lane32];
}

extern "C" void kernel_launch(void* const* d_in, const int* in_sizes, int n_in,
                              void* d_out, int out_size, void* d_ws, size_t ws_size,
                              hipStream_t stream) {
    const float* X  = (const float*)d_in[0];   // (B, D, 1) f32
    const float* L  = (const float*)d_in[1];   // (T, V, D) f32
    const int* idx  = (const int*)d_in[2];     // (B,) int
    float* out      = (float*)d_out;           // (B, D) f32

    char* ws = (char*)d_ws;
    int* counts               = (int*)ws;                              // 64 B
    unsigned long long* keys  = (unsigned long long*)(ws + 64);        // 16 KiB
    int* lists                = (int*)(ws + 64 + 16384);               // 128 KiB
    float* invnrm             = (float*)(ws + 64 + 16384 + 131072);    // 64 KiB

    hipLaunchKernelGGL(k_prep,   dim3(2048),        dim3(256), 0, stream, L, counts, keys, invnrm);
    hipLaunchKernelGGL(k_bucket, dim3(8),           dim3(256), 0, stream, idx, counts, lists);
    hipLaunchKernelGGL(k_score,  dim3(16, 16, 4),   dim3(256), 0, stream, X, L, counts, lists, invnrm, keys);
    hipLaunchKernelGGL(k_gather, dim3(256),         dim3(256), 0, stream, L, idx, keys, out);
}

// Round 3
// 31.890 us; speedup vs baseline: 2.6331x; 1.3262x over previous
//
#include <hip/hip_runtime.h>
#include <cstdint>

#define T_STEPS 16
#define V_VECS  1024
#define D_DIM   128
#define B_BATCH 2048

// ---------------------------------------------------------------------------
// k_bucket: single block, 1024 threads. Zeros counts + keys, builds per-step
// lists via LDS histogram (order within a list is irrelevant).
// ---------------------------------------------------------------------------
__global__ __launch_bounds__(1024) void k_bucket(const int* __restrict__ idx,
                                                 int* __restrict__ counts,
                                                 int* __restrict__ lists,
                                                 unsigned long long* __restrict__ keys) {
    __shared__ int cnt[T_STEPS];
    const int tid = threadIdx.x;
    if (tid < T_STEPS) cnt[tid] = 0;
    keys[tid] = 0ull;
    keys[tid + 1024] = 0ull;
    __syncthreads();
    #pragma unroll
    for (int b = tid; b < B_BATCH; b += 1024) {
        const int t = idx[b];
        const int pos = atomicAdd(&cnt[t], 1);
        lists[t * B_BATCH + pos] = b;
    }
    __syncthreads();
    if (tid < T_STEPS) counts[tid] = cnt[tid];
}

// ---------------------------------------------------------------------------
// k_score: register-tiled fp32 GEMM + fused norms + fused argmax.
// Grid (16 vtiles, 16 t, 2 z), block 256 = 16(tv) x 16(tb).
// A-tile (64v x 128k) staged ONCE per block, k-major; per-v inverse norms
// computed from the staged data (4 partials in LDS). In-block chunk loop
// (cs = z*64; cs < n; cs += 128) restages only the X-tile.
// Inner loop: per k, two ds_read_b128 (A 2-way aliased, X broadcast),
// 16 FMA into 4x4 accumulators. Epilogue: invnorm scale, per-thread argmax
// over 4 v, 4-step shfl_xor across tv lanes, atomicMax packed
// (ordered_score, 1023-v) key per b (ties -> lowest v, matches jnp.argmax).
// ---------------------------------------------------------------------------
__global__ __launch_bounds__(256) void k_score(const float* __restrict__ X,
                                               const float* __restrict__ L,
                                               const int* __restrict__ counts,
                                               const int* __restrict__ lists,
                                               unsigned long long* __restrict__ keys) {
    __shared__ __align__(16) float As[D_DIM][64];   // 32 KB
    __shared__ __align__(16) float Xs[D_DIM][64];   // 32 KB
    __shared__ float npart[4][64];
    __shared__ float invn_s[64];

    const int t  = blockIdx.y;
    const int v0 = blockIdx.x * 64;
    const int n  = counts[t];
    const int z  = blockIdx.z;
    if (z * 64 >= n) return;             // uniform exit, before any barrier

    const int tid  = threadIdx.x;
    const int lane = tid & 63;
    const int w    = tid >> 6;

    // ---- stage A^T once (k-major): row v = lane, float4 col k4 = w + 4p ----
    const float4* LA = (const float4*)(L + (size_t)(t * V_VECS + v0) * D_DIM);
    float ss = 0.f;
    #pragma unroll
    for (int p = 0; p < 8; ++p) {
        const int k4 = w + 4 * p;              // 0..31
        const float4 g = LA[lane * 32 + k4];
        As[4 * k4 + 0][lane] = g.x;
        As[4 * k4 + 1][lane] = g.y;
        As[4 * k4 + 2][lane] = g.z;
        As[4 * k4 + 3][lane] = g.w;
        ss += g.x * g.x + g.y * g.y + g.z * g.z + g.w * g.w;
    }
    npart[w][lane] = ss;
    __syncthreads();
    if (tid < 64) {
        const float s = npart[0][tid] + npart[1][tid] + npart[2][tid] + npart[3][tid];
        invn_s[tid] = rsqrtf(fmaxf(s, 1e-12f));
    }
    // invn_s becomes visible to all threads at the barrier after X staging.

    const int tv = tid & 15;     // v-group: v = v0 + tv*4 + i
    const int tb = tid >> 4;     // b-group: b-slot = cs + tb*4 + j
    const float4* XA = (const float4*)X;

    for (int cs = z * 64; cs < n; cs += 128) {
        __syncthreads();         // prior iter's Xs reads done; npart reads done

        // ---- stage X^T for this chunk: row = bucketed b (zero-pad past n) ----
        const int brow = cs + lane;
        const int bg = (brow < n) ? lists[t * B_BATCH + brow] : -1;
        #pragma unroll
        for (int p = 0; p < 8; ++p) {
            const int k4 = w + 4 * p;
            float4 g = make_float4(0.f, 0.f, 0.f, 0.f);
            if (bg >= 0) g = XA[bg * 32 + k4];
            Xs[4 * k4 + 0][lane] = g.x;
            Xs[4 * k4 + 1][lane] = g.y;
            Xs[4 * k4 + 2][lane] = g.z;
            Xs[4 * k4 + 3][lane] = g.w;
        }
        __syncthreads();

        float acc[4][4] = {};
        #pragma unroll 16
        for (int k = 0; k < D_DIM; ++k) {
            const float4 av = *(const float4*)&As[k][tv * 4];
            const float4 xb = *(const float4*)&Xs[k][tb * 4];
            const float a[4] = {av.x, av.y, av.z, av.w};
            const float x[4] = {xb.x, xb.y, xb.z, xb.w};
            #pragma unroll
            for (int i = 0; i < 4; ++i)
                #pragma unroll
                for (int j = 0; j < 4; ++j)
                    acc[i][j] += a[i] * x[j];
        }

        // ---- epilogue: argmax over v per b ----
        const float invp[4] = {invn_s[tv * 4 + 0], invn_s[tv * 4 + 1],
                               invn_s[tv * 4 + 2], invn_s[tv * 4 + 3]};

        #pragma unroll
        for (int j = 0; j < 4; ++j) {
            float s = acc[0][j] * invp[0];
            int   c = v0 + tv * 4;
            #pragma unroll
            for (int i = 1; i < 4; ++i) {
                const float si = acc[i][j] * invp[i];
                const int   ci = v0 + tv * 4 + i;
                if (si > s) { s = si; c = ci; }      // strict: lowest v wins tie
            }
            #pragma unroll
            for (int m = 8; m >= 1; m >>= 1) {       // reduce across tv lanes
                const float u  = __shfl_xor(s, m);
                const int   cu = __shfl_xor(c, m);
                if (u > s || (u == s && cu < c)) { s = u; c = cu; }
            }
            if (tv == 0) {
                const int bi = cs + tb * 4 + j;
                if (bi < n) {
                    const int b = lists[t * B_BATCH + bi];
                    unsigned int ub = __float_as_uint(s);
                    ub = (ub & 0x80000000u) ? ~ub : (ub | 0x80000000u);
                    const unsigned long long key =
                        ((unsigned long long)ub << 32) |
                        (unsigned long long)(unsigned)(1023 - c);
                    atomicMax(&keys[b], key);
                }
            }
        }
    }
}

// ---------------------------------------------------------------------------
// k_gather: decode winning v per b, copy raw vector (bit-exact) to out.
// ---------------------------------------------------------------------------
__global__ __launch_bounds__(256) void k_gather(const float* __restrict__ L,
                                                const int* __restrict__ idx,
                                                const unsigned long long* __restrict__ keys,
                                                float* __restrict__ out) {
    const int tid = threadIdx.x;
    const int b = blockIdx.x * 8 + (tid >> 5);
    const int lane32 = tid & 31;
    const unsigned long long key = keys[b];
    const int v = 1023 - (int)(key & 0xffffffffull);
    const int t = idx[b];
    ((float4*)out)[b * 32 + lane32] =
        ((const float4*)L)[(size_t)(t * V_VECS + v) * 32 + lane32];
}

extern "C" void kernel_launch(void* const* d_in, const int* in_sizes, int n_in,
                              void* d_out, int out_size, void* d_ws, size_t ws_size,
                              hipStream_t stream) {
    const float* X  = (const float*)d_in[0];   // (B, D, 1) f32
    const float* L  = (const float*)d_in[1];   // (T, V, D) f32
    const int* idx  = (const int*)d_in[2];     // (B,) int
    float* out      = (float*)d_out;           // (B, D) f32

    char* ws = (char*)d_ws;
    int* counts               = (int*)ws;                              // 64 B
    unsigned long long* keys  = (unsigned long long*)(ws + 64);        // 16 KiB
    int* lists                = (int*)(ws + 64 + 16384);               // 128 KiB

    hipLaunchKernelGGL(k_bucket, dim3(1),          dim3(1024), 0, stream, idx, counts, lists, keys);
    hipLaunchKernelGGL(k_score,  dim3(16, 16, 2),  dim3(256),  0, stream, X, L, counts, lists, keys);
    hipLaunchKernelGGL(k_gather, dim3(256),        dim3(256),  0, stream, L, idx, keys, out);
}